// Round 2
// baseline (278.381 us; speedup 1.0000x reference)
//
#include <hip/hip_runtime.h>

// MaskUnitAttention fused kernel, MI355X gfx950.
// B=64, N=3136 (=64 tokens * 49 windows, window-fastest), DIM=96, DIM_OUT=192,
// HEADS=2, HEAD_DIM=96, Q_STRIDE=4, WINDOW_SIZE=16.
// One block per (b, window): QKV gemm -> q maxpool -> softmax attn -> proj, fused.
// Dual-dtype: runtime sniff decides bf16 vs fp32 input interpretation; kernel is
// launched twice (one per mode), the non-matching instantiation returns immediately.

#define NW 49
#define NTOK 3136
#define DIM 96
#define DOUT 192

typedef __bf16 bf16x8 __attribute__((ext_vector_type(8)));
typedef float f32x4 __attribute__((ext_vector_type(4)));
typedef unsigned short u16x8 __attribute__((ext_vector_type(8)));
typedef unsigned short u16x4 __attribute__((ext_vector_type(4)));

__device__ __forceinline__ unsigned short f2bf(float f) {
    unsigned int u = __builtin_bit_cast(unsigned int, f);
    u = (u + 0x7FFFu + ((u >> 16) & 1u)) >> 16;   // RNE
    return (unsigned short)u;
}
__device__ __forceinline__ float bf2f(unsigned short h) {
    unsigned int u = ((unsigned int)h) << 16;
    return __builtin_bit_cast(float, u);
}

// Data sniff: x ~ N(0,1). bf16 data -> even-indexed u16s all have sane exponents.
// fp32 data -> even-indexed u16s are mantissa low-halves (uniform) -> ~16% sane.
__device__ __forceinline__ bool sniff_fp32(const unsigned short* x16) {
    int sane = 0;
    #pragma unroll
    for (int i = 0; i < 32; ++i) {
        unsigned e = ((unsigned)x16[2 * i] >> 7) & 0xFFu;
        sane += (e >= 100u && e <= 141u) ? 1 : 0;   // |v| in [2^-27, 2^14]
    }
    return sane < 24;
}

// Load an 8-wide bf16 fragment from a row-major weight/x row (dual dtype).
template <bool FP32>
__device__ __forceinline__ bf16x8 ldrow(const void* w, size_t row, int rowstride, int col) {
    if constexpr (!FP32) {
        const unsigned short* p = (const unsigned short*)w + row * rowstride + col;
        return __builtin_bit_cast(bf16x8, *(const u16x8*)p);
    } else {
        const float* p = (const float*)w + row * rowstride + col;
        f32x4 a = *(const f32x4*)p;
        f32x4 b = *(const f32x4*)(p + 4);
        u16x8 r;
        r[0] = f2bf(a[0]); r[1] = f2bf(a[1]); r[2] = f2bf(a[2]); r[3] = f2bf(a[3]);
        r[4] = f2bf(b[0]); r[5] = f2bf(b[1]); r[6] = f2bf(b[2]); r[7] = f2bf(b[3]);
        return __builtin_bit_cast(bf16x8, r);
    }
}
__device__ __forceinline__ bf16x8 ldlds(const unsigned short* p) {
    return __builtin_bit_cast(bf16x8, *(const u16x8*)p);
}

template <bool FP32>
__global__ __launch_bounds__(256, 2)
void mua_kernel(const void* __restrict__ x,
                const void* __restrict__ w_qkv,
                const void* __restrict__ b_qkv,
                const void* __restrict__ w_proj,
                const void* __restrict__ b_proj,
                void* __restrict__ out)
{
    if (sniff_fp32((const unsigned short*)x) != FP32) return;

    const int bid = blockIdx.x;
    const int b   = bid / NW;
    const int wi  = bid - b * NW;
    const int tid  = threadIdx.x;
    const int wave = tid >> 6;
    const int lane = tid & 63;
    const int quad = lane >> 4;
    const int l16  = lane & 15;

    // 64 KiB LDS, manually carved. Padded strides (104/72/200 u16) are 16B-multiples
    // and give <=2-way bank aliasing (free). Regions:
    //   k_s  [2][64][104]  @ 0      (x_s [64][104] aliases head-0 half; x dead after B2)
    //   v_s  [2][96][72]   @ 13312  (v transposed: [head][d][t])
    //   qp_s [2][16][104]  @ 27136  (o_s [16][200] aliases; qp dead after B4)
    //   p_s  [2][16][72]   @ 30464
    __shared__ __attribute__((aligned(16))) unsigned short lds[32768];
    unsigned short* k_s  = lds;
    unsigned short* v_s  = lds + 13312;
    unsigned short* qp_s = lds + 27136;
    unsigned short* p_s  = lds + 30464;
    unsigned short* x_s  = k_s;
    unsigned short* o_s  = qp_s;

    // ---- phase 0: zero-init LDS (NaN-proofing: any coverage bug reads 0.0) ----
    {
        u16x8 z = (u16x8){0, 0, 0, 0, 0, 0, 0, 0};
        #pragma unroll
        for (int i = 0; i < 16; ++i)
            *(u16x8*)&lds[(tid + i * 256) * 8] = z;
    }
    __syncthreads();

    // ---- phase 1: stage x tile (64 rows x 96, rows strided by 49*96 in global) ----
    {
        const size_t xoff = ((size_t)b * NTOK + wi) * DIM;
        #pragma unroll
        for (int i = 0; i < 3; ++i) {
            int chunk = tid + i * 256;          // 768 = 64 rows * 12 chunks
            int row = chunk / 12;
            int c16 = chunk - row * 12;
            bf16x8 vv;
            if constexpr (!FP32)
                vv = ldrow<false>((const unsigned short*)x + xoff, (size_t)row, NW * DIM, c16 * 8);
            else
                vv = ldrow<true>((const float*)x + xoff, (size_t)row, NW * DIM, c16 * 8);
            *(u16x8*)&x_s[row * 104 + c16 * 8] = __builtin_bit_cast(u16x8, vv);
        }
    }
    __syncthreads();   // B1: x staged

    // ---- phase 2: A-fragments of x into registers ----
    bf16x8 afr[4][3];
    #pragma unroll
    for (int mt = 0; mt < 4; ++mt)
        #pragma unroll
        for (int ks = 0; ks < 3; ++ks)
            afr[mt][ks] = ldlds(&x_s[(mt * 16 + l16) * 104 + ks * 32 + quad * 8]);
    __syncthreads();   // B2: x region free -> k head 0 may overwrite

    // ---- phase 3: GEMM1 qkv = x @ w_qkv^T + b_qkv; wave owns 144 of 576 channels ----
    const int nbase = wave * 144;
    bf16x8 bfr[2][3];
    #pragma unroll
    for (int ks = 0; ks < 3; ++ks)
        bfr[0][ks] = ldrow<FP32>(w_qkv, (size_t)(nbase + l16), DIM, ks * 32 + quad * 8);
    #pragma unroll
    for (int nt = 0; nt < 9; ++nt) {
        const int cur = nt & 1, nxt = cur ^ 1;
        if (nt < 8) {
            #pragma unroll
            for (int ks = 0; ks < 3; ++ks)
                bfr[nxt][ks] = ldrow<FP32>(w_qkv, (size_t)(nbase + (nt + 1) * 16 + l16), DIM, ks * 32 + quad * 8);
        }
        f32x4 acc[4];
        #pragma unroll
        for (int mt = 0; mt < 4; ++mt) {
            acc[mt] = (f32x4){0.f, 0.f, 0.f, 0.f};
            #pragma unroll
            for (int ks = 0; ks < 3; ++ks)
                acc[mt] = __builtin_amdgcn_mfma_f32_16x16x32_bf16(afr[mt][ks], bfr[cur][ks], acc[mt], 0, 0, 0);
        }
        // C-layout: col(channel) = l16, row(token) = quad*4 + r (+ mt*16)
        const int c = nbase + nt * 16 + l16;
        const float bias = FP32 ? ((const float*)b_qkv)[c] : bf2f(((const unsigned short*)b_qkv)[c]);
        const int type = c / 192;
        const int hd   = (c % 192) / 96;
        const int d    = c % 96;
        if (type == 0) {
            // q maxpool: pool groups t = mt*16 + j are exactly the 4 M-tiles
            #pragma unroll
            for (int r = 0; r < 4; ++r) {
                float m = fmaxf(fmaxf(acc[0][r], acc[1][r]), fmaxf(acc[2][r], acc[3][r])) + bias;
                qp_s[(hd * 16 + quad * 4 + r) * 104 + d] = f2bf(m);
            }
        } else if (type == 1) {
            #pragma unroll
            for (int mt = 0; mt < 4; ++mt)
                #pragma unroll
                for (int r = 0; r < 4; ++r)
                    k_s[hd * 6656 + (mt * 16 + quad * 4 + r) * 104 + d] = f2bf(acc[mt][r] + bias);
        } else {
            // v transposed [d][t]; 4 consecutive t per (lane,mt) -> packed 8B write
            #pragma unroll
            for (int mt = 0; mt < 4; ++mt) {
                u16x4 pk;
                #pragma unroll
                for (int r = 0; r < 4; ++r) pk[r] = f2bf(acc[mt][r] + bias);
                *(u16x4*)&v_s[hd * 6912 + d * 72 + mt * 16 + quad * 4] = pk;
            }
        }
    }
    __syncthreads();   // B3: qp/k/v ready

    // ---- phase 4: S = qp @ k^T, row softmax (rows j = quad*4+r, cols spread on l16/nt) ----
    const int h   = wave >> 1;
    const int sub = wave & 1;
    bf16x8 qa[3];
    #pragma unroll
    for (int ks = 0; ks < 3; ++ks)
        qa[ks] = ldlds(&qp_s[(h * 16 + l16) * 104 + ks * 32 + quad * 8]);
    f32x4 s[4];
    #pragma unroll
    for (int nt = 0; nt < 4; ++nt) {
        s[nt] = (f32x4){0.f, 0.f, 0.f, 0.f};
        #pragma unroll
        for (int ks = 0; ks < 3; ++ks) {
            bf16x8 kb = ldlds(&k_s[h * 6656 + (nt * 16 + l16) * 104 + ks * 32 + quad * 8]);
            s[nt] = __builtin_amdgcn_mfma_f32_16x16x32_bf16(qa[ks], kb, s[nt], 0, 0, 0);
        }
    }
    float rinv[4];
    const float cexp = 0.10206207262f * 1.44269504089f;  // 96^-0.5 * log2(e)
    #pragma unroll
    for (int r = 0; r < 4; ++r) {
        float m = fmaxf(fmaxf(s[0][r], s[1][r]), fmaxf(s[2][r], s[3][r]));
        m = fmaxf(m, __shfl_xor(m, 1));
        m = fmaxf(m, __shfl_xor(m, 2));
        m = fmaxf(m, __shfl_xor(m, 4));
        m = fmaxf(m, __shfl_xor(m, 8));
        float sum = 0.f;
        #pragma unroll
        for (int nt = 0; nt < 4; ++nt) {
            s[nt][r] = exp2f((s[nt][r] - m) * cexp);
            sum += s[nt][r];
        }
        sum += __shfl_xor(sum, 1);
        sum += __shfl_xor(sum, 2);
        sum += __shfl_xor(sum, 4);
        sum += __shfl_xor(sum, 8);
        rinv[r] = 1.0f / sum;
    }
    if (sub == 0) {   // wave pair computes S redundantly; one writer
        #pragma unroll
        for (int nt = 0; nt < 4; ++nt)
            #pragma unroll
            for (int r = 0; r < 4; ++r)
                p_s[h * 1152 + (quad * 4 + r) * 72 + nt * 16 + l16] = f2bf(s[nt][r]);
    }
    __syncthreads();   // B4: P ready; qp dead -> o_s may overwrite

    // ---- phase 5: O = P @ V (3 of 6 d-tiles per sub-wave), scale rows by 1/sum ----
    bf16x8 pa[2];
    #pragma unroll
    for (int ks = 0; ks < 2; ++ks)
        pa[ks] = ldlds(&p_s[h * 1152 + l16 * 72 + ks * 32 + quad * 8]);
    #pragma unroll
    for (int i = 0; i < 3; ++i) {
        const int n0 = (sub * 3 + i) * 16;
        f32x4 oacc = (f32x4){0.f, 0.f, 0.f, 0.f};
        #pragma unroll
        for (int ks = 0; ks < 2; ++ks) {
            bf16x8 vb = ldlds(&v_s[h * 6912 + (n0 + l16) * 72 + ks * 32 + quad * 8]);
            oacc = __builtin_amdgcn_mfma_f32_16x16x32_bf16(pa[ks], vb, oacc, 0, 0, 0);
        }
        #pragma unroll
        for (int r = 0; r < 4; ++r)
            o_s[(quad * 4 + r) * 200 + h * 96 + n0 + l16] = f2bf(oacc[r] * rinv[r]);
    }
    __syncthreads();   // B5: o ready

    // ---- phase 6: out = o @ w_proj^T + b_proj; wave owns 48 of 192 channels ----
    bf16x8 oa[6];
    #pragma unroll
    for (int ks = 0; ks < 6; ++ks)
        oa[ks] = ldlds(&o_s[l16 * 200 + ks * 32 + quad * 8]);
    const int cbase = wave * 48;
    #pragma unroll
    for (int i = 0; i < 3; ++i) {
        const int c = cbase + i * 16 + l16;
        f32x4 acc = (f32x4){0.f, 0.f, 0.f, 0.f};
        #pragma unroll
        for (int ks = 0; ks < 6; ++ks) {
            bf16x8 wb = ldrow<FP32>(w_proj, (size_t)c, DOUT, ks * 32 + quad * 8);
            acc = __builtin_amdgcn_mfma_f32_16x16x32_bf16(oa[ks], wb, acc, 0, 0, 0);
        }
        const float bias = FP32 ? ((const float*)b_proj)[c] : bf2f(((const unsigned short*)b_proj)[c]);
        #pragma unroll
        for (int r = 0; r < 4; ++r) {
            const int m = quad * 4 + r;          // out row = b*784 + m*49 + wi
            const size_t idx = ((size_t)(b * 784 + m * NW + wi)) * DOUT + c;
            if constexpr (FP32) ((float*)out)[idx] = acc[r] + bias;
            else                ((unsigned short*)out)[idx] = f2bf(acc[r] + bias);
        }
    }
}

extern "C" void kernel_launch(void* const* d_in, const int* in_sizes, int n_in,
                              void* d_out, int out_size, void* d_ws, size_t ws_size,
                              hipStream_t stream) {
    const void* x      = d_in[0];
    const void* w_qkv  = d_in[1];
    const void* b_qkv  = d_in[2];
    const void* w_proj = d_in[3];
    const void* b_proj = d_in[4];
    dim3 grid(64 * NW), block(256);
    // Launch both dtype modes; the non-matching one returns immediately.
    hipLaunchKernelGGL((mua_kernel<false>), grid, block, 0, stream, x, w_qkv, b_qkv, w_proj, b_proj, d_out);
    hipLaunchKernelGGL((mua_kernel<true>),  grid, block, 0, stream, x, w_qkv, b_qkv, w_proj, b_proj, d_out);
}

// Round 6
// 276.886 us; speedup vs baseline: 1.0054x; 1.0054x over previous
//
#include <hip/hip_runtime.h>

// MaskUnitAttention fused kernel, MI355X gfx950.
// B=64, N=3136 (=64 tokens * 49 windows, window-fastest), DIM=96, DIM_OUT=192,
// HEADS=2, HEAD_DIM=96, Q_STRIDE=4, WINDOW_SIZE=16.
// One block per (b, window): QKV gemm -> q maxpool -> softmax attn -> proj, fused.
// Dual-dtype: runtime sniff decides bf16 vs fp32 input interpretation; kernel is
// launched twice (one per mode), the non-matching instantiation returns immediately.

#define NW 49
#define NTOK 3136
#define DIM 96
#define DOUT 192

typedef __bf16 bf16x8 __attribute__((ext_vector_type(8)));
typedef float f32x4 __attribute__((ext_vector_type(4)));
typedef unsigned short u16x8 __attribute__((ext_vector_type(8)));
typedef unsigned short u16x4 __attribute__((ext_vector_type(4)));

__device__ __forceinline__ unsigned short f2bf(float f) {
    unsigned int u = __builtin_bit_cast(unsigned int, f);
    u = (u + 0x7FFFu + ((u >> 16) & 1u)) >> 16;   // RNE
    return (unsigned short)u;
}
__device__ __forceinline__ float bf2f(unsigned short h) {
    unsigned int u = ((unsigned int)h) << 16;
    return __builtin_bit_cast(float, u);
}

// Data sniff: x ~ N(0,1). bf16 data -> even-indexed u16s all have sane exponents.
// fp32 data -> even-indexed u16s are mantissa low-halves (uniform) -> ~16% sane.
__device__ __forceinline__ bool sniff_fp32(const unsigned short* x16) {
    int sane = 0;
    #pragma unroll
    for (int i = 0; i < 32; ++i) {
        unsigned e = ((unsigned)x16[2 * i] >> 7) & 0xFFu;
        sane += (e >= 100u && e <= 141u) ? 1 : 0;   // |v| in [2^-27, 2^14]
    }
    return sane < 24;
}

// Load an 8-wide bf16 fragment from a row-major weight/x row (dual dtype).
template <bool FP32>
__device__ __forceinline__ bf16x8 ldrow(const void* w, size_t row, int rowstride, int col) {
    if constexpr (!FP32) {
        const unsigned short* p = (const unsigned short*)w + row * rowstride + col;
        return __builtin_bit_cast(bf16x8, *(const u16x8*)p);
    } else {
        const float* p = (const float*)w + row * rowstride + col;
        f32x4 a = *(const f32x4*)p;
        f32x4 b = *(const f32x4*)(p + 4);
        u16x8 r;
        r[0] = f2bf(a[0]); r[1] = f2bf(a[1]); r[2] = f2bf(a[2]); r[3] = f2bf(a[3]);
        r[4] = f2bf(b[0]); r[5] = f2bf(b[1]); r[6] = f2bf(b[2]); r[7] = f2bf(b[3]);
        return __builtin_bit_cast(bf16x8, r);
    }
}
__device__ __forceinline__ bf16x8 ldlds(const unsigned short* p) {
    return __builtin_bit_cast(bf16x8, *(const u16x8*)p);
}

template <bool FP32>
__global__ __launch_bounds__(256, 2)
void mua_kernel(const void* __restrict__ x,
                const void* __restrict__ w_qkv,
                const void* __restrict__ b_qkv,
                const void* __restrict__ w_proj,
                const void* __restrict__ b_proj,
                void* __restrict__ out)
{
    if (sniff_fp32((const unsigned short*)x) != FP32) return;

    const int bid = blockIdx.x;
    const int b   = bid / NW;
    const int wi  = bid - b * NW;
    const int tid  = threadIdx.x;
    const int wave = tid >> 6;
    const int lane = tid & 63;
    const int quad = lane >> 4;
    const int l16  = lane & 15;

    // 64 KiB LDS, manually carved. Padded strides (104/72/200 u16) are 16B-multiples
    // and give <=2-way bank aliasing (free). Regions:
    //   k_s  [2][64][104]  @ 0      (x_s [64][104] aliases head-0 half; x dead after B2)
    //   v_s  [2][96][72]   @ 13312  (v transposed: [head][d][t])
    //   qp_s [2][16][104]  @ 27136  (o_s [16][200] aliases; qp dead after B4)
    //   p_s  [2][16][72]   @ 30464
    __shared__ __attribute__((aligned(16))) unsigned short lds[32768];
    unsigned short* k_s  = lds;
    unsigned short* v_s  = lds + 13312;
    unsigned short* qp_s = lds + 27136;
    unsigned short* p_s  = lds + 30464;
    unsigned short* x_s  = k_s;
    unsigned short* o_s  = qp_s;

    // ---- phase 0: zero-init LDS (NaN-proofing: any coverage bug reads 0.0) ----
    {
        u16x8 z = (u16x8){0, 0, 0, 0, 0, 0, 0, 0};
        #pragma unroll
        for (int i = 0; i < 16; ++i)
            *(u16x8*)&lds[(tid + i * 256) * 8] = z;
    }
    __syncthreads();

    // ---- phase 1: stage x tile (64 rows x 96, rows strided by 49*96 in global) ----
    {
        const size_t xoff = ((size_t)b * NTOK + wi) * DIM;
        #pragma unroll
        for (int i = 0; i < 3; ++i) {
            int chunk = tid + i * 256;          // 768 = 64 rows * 12 chunks
            int row = chunk / 12;
            int c16 = chunk - row * 12;
            bf16x8 vv;
            if constexpr (!FP32)
                vv = ldrow<false>((const unsigned short*)x + xoff, (size_t)row, NW * DIM, c16 * 8);
            else
                vv = ldrow<true>((const float*)x + xoff, (size_t)row, NW * DIM, c16 * 8);
            *(u16x8*)&x_s[row * 104 + c16 * 8] = __builtin_bit_cast(u16x8, vv);
        }
    }
    __syncthreads();   // B1: x staged

    // ---- phase 2: A-fragments of x into registers ----
    bf16x8 afr[4][3];
    #pragma unroll
    for (int mt = 0; mt < 4; ++mt)
        #pragma unroll
        for (int ks = 0; ks < 3; ++ks)
            afr[mt][ks] = ldlds(&x_s[(mt * 16 + l16) * 104 + ks * 32 + quad * 8]);
    __syncthreads();   // B2: x region free -> k head 0 may overwrite

    // ---- phase 3: GEMM1 qkv = x @ w_qkv^T + b_qkv; wave owns 144 of 576 channels ----
    const int nbase = wave * 144;
    bf16x8 bfr[2][3];
    #pragma unroll
    for (int ks = 0; ks < 3; ++ks)
        bfr[0][ks] = ldrow<FP32>(w_qkv, (size_t)(nbase + l16), DIM, ks * 32 + quad * 8);
    #pragma unroll
    for (int nt = 0; nt < 9; ++nt) {
        const int cur = nt & 1, nxt = cur ^ 1;
        if (nt < 8) {
            #pragma unroll
            for (int ks = 0; ks < 3; ++ks)
                bfr[nxt][ks] = ldrow<FP32>(w_qkv, (size_t)(nbase + (nt + 1) * 16 + l16), DIM, ks * 32 + quad * 8);
        }
        f32x4 acc[4];
        #pragma unroll
        for (int mt = 0; mt < 4; ++mt) {
            acc[mt] = (f32x4){0.f, 0.f, 0.f, 0.f};
            #pragma unroll
            for (int ks = 0; ks < 3; ++ks)
                acc[mt] = __builtin_amdgcn_mfma_f32_16x16x32_bf16(afr[mt][ks], bfr[cur][ks], acc[mt], 0, 0, 0);
        }
        // C-layout: col(channel) = l16, row(token) = quad*4 + r (+ mt*16)
        const int c = nbase + nt * 16 + l16;
        const float bias = FP32 ? ((const float*)b_qkv)[c] : bf2f(((const unsigned short*)b_qkv)[c]);
        const int type = c / 192;
        const int hd   = (c % 192) / 96;
        const int d    = c % 96;
        if (type == 0) {
            // q maxpool: pool groups t = mt*16 + j are exactly the 4 M-tiles
            #pragma unroll
            for (int r = 0; r < 4; ++r) {
                float m = fmaxf(fmaxf(acc[0][r], acc[1][r]), fmaxf(acc[2][r], acc[3][r])) + bias;
                qp_s[(hd * 16 + quad * 4 + r) * 104 + d] = f2bf(m);
            }
        } else if (type == 1) {
            #pragma unroll
            for (int mt = 0; mt < 4; ++mt)
                #pragma unroll
                for (int r = 0; r < 4; ++r)
                    k_s[hd * 6656 + (mt * 16 + quad * 4 + r) * 104 + d] = f2bf(acc[mt][r] + bias);
        } else {
            // v transposed [d][t]; 4 consecutive t per (lane,mt) -> packed 8B write
            #pragma unroll
            for (int mt = 0; mt < 4; ++mt) {
                u16x4 pk;
                #pragma unroll
                for (int r = 0; r < 4; ++r) pk[r] = f2bf(acc[mt][r] + bias);
                *(u16x4*)&v_s[hd * 6912 + d * 72 + mt * 16 + quad * 4] = pk;
            }
        }
    }
    __syncthreads();   // B3: qp/k/v ready

    // ---- phase 4: S = qp @ k^T, row softmax (rows j = quad*4+r, cols spread on l16/nt) ----
    const int h   = wave >> 1;
    const int sub = wave & 1;
    bf16x8 qa[3];
    #pragma unroll
    for (int ks = 0; ks < 3; ++ks)
        qa[ks] = ldlds(&qp_s[(h * 16 + l16) * 104 + ks * 32 + quad * 8]);
    f32x4 s[4];
    #pragma unroll
    for (int nt = 0; nt < 4; ++nt) {
        s[nt] = (f32x4){0.f, 0.f, 0.f, 0.f};
        #pragma unroll
        for (int ks = 0; ks < 3; ++ks) {
            bf16x8 kb = ldlds(&k_s[h * 6656 + (nt * 16 + l16) * 104 + ks * 32 + quad * 8]);
            s[nt] = __builtin_amdgcn_mfma_f32_16x16x32_bf16(qa[ks], kb, s[nt], 0, 0, 0);
        }
    }
    float rinv[4];
    const float cexp = 0.10206207261596576f * 1.4426950408889634f;  // 96^-0.5 * log2e
    #pragma unroll
    for (int r = 0; r < 4; ++r) {
        float m = fmaxf(fmaxf(s[0][r], s[1][r]), fmaxf(s[2][r], s[3][r]));
        m = fmaxf(m, __shfl_xor(m, 1));
        m = fmaxf(m, __shfl_xor(m, 2));
        m = fmaxf(m, __shfl_xor(m, 4));
        m = fmaxf(m, __shfl_xor(m, 8));
        float sum = 0.f;
        #pragma unroll
        for (int nt = 0; nt < 4; ++nt) {
            s[nt][r] = exp2f((s[nt][r] - m) * cexp);
            sum += s[nt][r];
        }
        sum += __shfl_xor(sum, 1);
        sum += __shfl_xor(sum, 2);
        sum += __shfl_xor(sum, 4);
        sum += __shfl_xor(sum, 8);
        rinv[r] = 1.0f / sum;
    }
    if (sub == 0) {   // wave pair computes S redundantly; one writer
        #pragma unroll
        for (int nt = 0; nt < 4; ++nt)
            #pragma unroll
            for (int r = 0; r < 4; ++r)
                p_s[h * 1152 + (quad * 4 + r) * 72 + nt * 16 + l16] = f2bf(s[nt][r]);
    }
    __syncthreads();   // B4: P ready; qp dead -> o may overwrite

    // ---- phase 5: O = P @ V (3 of 6 d-tiles per sub-wave), scale rows by 1/sum ----
    bf16x8 pa[2];
    #pragma unroll
    for (int ks = 0; ks < 2; ++ks)
        pa[ks] = ldlds(&p_s[h * 1152 + l16 * 72 + ks * 32 + quad * 8]);
    #pragma unroll
    for (int i = 0; i < 3; ++i) {
        const int n0 = (sub * 3 + i) * 16;
        f32x4 oacc = (f32x4){0.f, 0.f, 0.f, 0.f};
        #pragma unroll
        for (int ks = 0; ks < 2; ++ks) {
            bf16x8 vb = ldlds(&v_s[h * 6912 + (n0 + l16) * 72 + ks * 32 + quad * 8]);
            oacc = __builtin_amdgcn_mfma_f32_16x16x32_bf16(pa[ks], vb, oacc, 0, 0, 0);
        }
        #pragma unroll
        for (int r = 0; r < 4; ++r)
            o_s[(quad * 4 + r) * 200 + h * 96 + n0 + l16] = f2bf(oacc[r] * rinv[r]);
    }
    __syncthreads();   // B5: o ready

    // ---- phase 6: out = o @ w_proj^T + b_proj; wave owns 48 of 192 channels ----
    bf16x8 oa[6];
    #pragma unroll
    for (int ks = 0; ks < 6; ++ks)
        oa[ks] = ldlds(&o_s[l16 * 200 + ks * 32 + quad * 8]);
    const int cbase = wave * 48;
    #pragma unroll
    for (int i = 0; i < 3; ++i) {
        const int c = cbase + i * 16 + l16;
        f32x4 acc = (f32x4){0.f, 0.f, 0.f, 0.f};
        #pragma unroll
        for (int ks = 0; ks < 6; ++ks) {
            bf16x8 wb = ldrow<FP32>(w_proj, (size_t)c, DOUT, ks * 32 + quad * 8);
            acc = __builtin_amdgcn_mfma_f32_16x16x32_bf16(oa[ks], wb, acc, 0, 0, 0);
        }
        const float bias = FP32 ? ((const float*)b_proj)[c] : bf2f(((const unsigned short*)b_proj)[c]);
        #pragma unroll
        for (int r = 0; r < 4; ++r) {
            const int m = quad * 4 + r;          // out row = b*784 + m*49 + wi
            const size_t idx = ((size_t)(b * 784 + m * NW + wi)) * DOUT + c;
            if constexpr (FP32) ((float*)out)[idx] = acc[r] + bias;
            else                ((unsigned short*)out)[idx] = f2bf(acc[r] + bias);
        }
    }
}

extern "C" void kernel_launch(void* const* d_in, const int* in_sizes, int n_in,
                              void* d_out, int out_size, void* d_ws, size_t ws_size,
                              hipStream_t stream) {
    const void* x      = d_in[0];
    const void* w_qkv  = d_in[1];
    const void* b_qkv  = d_in[2];
    const void* w_proj = d_in[3];
    const void* b_proj = d_in[4];
    dim3 grid(64 * NW), block(256);
    // Launch both dtype modes; the non-matching one returns immediately.
    hipLaunchKernelGGL((mua_kernel<false>), grid, block, 0, stream, x, w_qkv, b_qkv, w_proj, b_proj, d_out);
    hipLaunchKernelGGL((mua_kernel<true>),  grid, block, 0, stream, x, w_qkv, b_qkv, w_proj, b_proj, d_out);
}